// Round 5
// baseline (547.460 us; speedup 1.0000x reference)
//
#include <hip/hip_runtime.h>
#include <hip/hip_bf16.h>
#include <math.h>

typedef __bf16 bf16;
typedef __attribute__((ext_vector_type(2))) __bf16 bf16x2;
typedef __attribute__((ext_vector_type(4))) __bf16 bf16x4;
typedef __attribute__((ext_vector_type(8))) __bf16 bf16x8;
typedef __attribute__((ext_vector_type(4))) float f32x4;

#define LDS_ASYNC16(gptr, lptr)                                                        \
  __builtin_amdgcn_global_load_lds(                                                    \
      (const __attribute__((address_space(1))) void*)(gptr),                           \
      (__attribute__((address_space(3))) void*)(lptr), 16, 0, 0)

constexpr int BATCH = 2, SEQ = 2048, DIM = 2048, NH = 16, HD = 128;
// 1/sqrt(128) * log2(e): folded into Q at projection; flash works in exp2 domain
constexpr float QSC = 0.12751744f;
constexpr float FREQC = 0.20762050593046f;  // log2(10000)/64

// ---- DPP 16-lane reductions (row_ror rotates within 16-lane rows on gfx9) ----
template <int CTRL>
__device__ __forceinline__ float dpp_mov_f(float x) {
  return __int_as_float(__builtin_amdgcn_update_dpp(
      __float_as_int(x), __float_as_int(x), CTRL, 0xf, 0xf, false));
}
__device__ __forceinline__ float rowmax16(float x) {
  x = fmaxf(x, dpp_mov_f<0x121>(x));  // ror:1
  x = fmaxf(x, dpp_mov_f<0x122>(x));  // ror:2
  x = fmaxf(x, dpp_mov_f<0x124>(x));  // ror:4
  x = fmaxf(x, dpp_mov_f<0x128>(x));  // ror:8
  return x;
}
__device__ __forceinline__ float rowsum16(float x) {
  x += dpp_mov_f<0x121>(x);
  x += dpp_mov_f<0x122>(x);
  x += dpp_mov_f<0x124>(x);
  x += dpp_mov_f<0x128>(x);
  return x;
}

// ---------------------------------------------------------------- fp32 -> bf16
__global__ void cvt_f32_to_bf16(const float4* __restrict__ in,
                                bf16x4* __restrict__ out, int n4) {
  int i = blockIdx.x * blockDim.x + threadIdx.x;
  if (i >= n4) return;
  float4 v = in[i];
  bf16x4 o;
  o[0] = (bf16)v.x; o[1] = (bf16)v.y; o[2] = (bf16)v.z; o[3] = (bf16)v.w;
  out[i] = o;
}

// ------------------------- all 4 weights: W (K,N) fp32 -> W^T (N,K) bf16, z=which
__global__ void transpose_w4(const float* __restrict__ W0, const float* __restrict__ W1,
                             const float* __restrict__ W2, const float* __restrict__ W3,
                             bf16* __restrict__ T0, bf16* __restrict__ T3) {
  __shared__ float tile[32][33];
  const int z = blockIdx.z;
  const float* W = (z == 0) ? W0 : (z == 1) ? W1 : (z == 2) ? W2 : W3;
  bf16* WT = (z == 3) ? T3 : (T0 + (size_t)z * DIM * DIM);
  int tx = threadIdx.x, ty = threadIdx.y;
  int bx = blockIdx.x * 32, by = blockIdx.y * 32;
#pragma unroll
  for (int j = 0; j < 32; j += 8)
    tile[ty + j][tx] = W[(size_t)(by + ty + j) * DIM + bx + tx];
  __syncthreads();
#pragma unroll
  for (int j = 0; j < 32; j += 8)
    WT[(size_t)(bx + ty + j) * DIM + by + tx] = (bf16)tile[tx][ty + j];
}

// ============ 128x256 fused QKV GEMM + RoPE, B-direct-from-global ============
// R4 theory: all prior variants were LDS-BANDWIDTH-bound (per K-tile: A 32KBx4
// re-read + B 32KBx2 re-read + 64KB writes = 256KB LDS traffic vs 620 cyc MFMA
// -> hard ~25-30% ceiling, structure-invariant; matches R0-R3 within noise).
// Fix: B never touches LDS -- each wave loads its B-fragments straight from
// global (L2-resident panels) into VGPRs, double-buffered one K-tile ahead.
// A stays LDS-staged (x4 re-read is what LDS broadcast is for).
//   BM=128, BN=256, BK=64; 512 thr = 8 waves (2M x 4N), wave tile 64x64.
//   Grid 32x24 = 768 = EXACTLY 3 rounds of 256 CUs (no tail quantization).
//   LDS: A only, 3 bufs x 2 kh x [128 rows][32 k] (8 KB) = 48 KB. 3-buffer
//   rotation makes stage(t+2) WAR-safe vs reads(t) with one barrier/tile
//   (buf read at t-1 is re-staged at t, after the t-1 end barrier).
//   LDS traffic/K-tile: 16 w + 64 r = 80KB (3.2x less than R3's 256KB).
// vmcnt ledger (per tile t): issue B(t+1) x8 (global->VGPR), then A(t+2) x2
//   (global_load_lds). Tile-end s_waitcnt vmcnt(10) -> A(t+1) (issued last
//   tile, 10 ops deep) has landed; B(t+1)/A(t+2) stay in flight. Tail:
//   t=NT-2 issues only B x8 -> vmcnt(8); t=NT-1 issues nothing, no wait.
//   B-reg reads are compiler-auto-waited (dataflow). asm "memory" clobbers
//   pin issue order across tile boundaries.
// A-region layout [row][k8chunk] linear; reads (16 rows x 16B per quarter-wave,
// row stride 64B) land 8 lanes on each of 8 bank-groups = conflict-free, no
// swizzle needed. gload_lds dest: wave-uniform base + lane*16 (linear).
__device__ __forceinline__ void stage_A(const bf16* __restrict__ src, int m0, int ks,
                                        bf16* lds, int w, int tid) {
  const int row = tid >> 2;                 // 128 rows, 4 chunks/row
  const int ch = tid & 3;
  LDS_ASYNC16(src + (size_t)(m0 + row) * DIM + ks + ch * 8,
              lds + (size_t)(w * 64) * 8);  // wave-uniform base (+lane*16B in HW)
}

__global__ __launch_bounds__(512) void gemm_qkv(const bf16* __restrict__ A,
                                                const bf16* __restrict__ BT,
                                                bf16* __restrict__ Qb,
                                                bf16* __restrict__ Kb,
                                                bf16* __restrict__ VTo) {
  constexpr int ARSZ = 128 * 32;  // 4096 elems = 8 KB per (buf,kh) region
  constexpr int NT = DIM / 64;    // 32 K-tiles
  __shared__ __attribute__((aligned(16))) bf16 As[3 * 2 * ARSZ];  // 48 KB
  const int tid = threadIdx.x;
  const int w = tid >> 6, lane = tid & 63;
  const int quad = lane >> 4, ln = lane & 15;
  const int wm = w >> 2, wn = w & 3;  // 2M x 4N wave grid
  // XCD-bijective swizzle: each XCD owns 8 by x 12 bx -> its 4 MB L2 holds the
  // 8 A-panels (4 MB) while streaming B panels.
  const int lb = blockIdx.x;
  const int xcd = lb & 7, i = lb >> 3;        // i in 0..95
  const int by = (xcd >> 1) * 8 + (i & 7);    // 0..31
  const int bx = (xcd & 1) * 12 + (i >> 3);   // 0..23
  const int m0 = by * 128, n0 = bx * 256;
  const int aoff = wm * 64 + ln;              // A frag row within block tile
  const int qc = quad * 8;                    // k-subchunk within 32
  const bf16* bbase = BT + (size_t)(n0 + wn * 64 + ln) * DIM + qc;

  f32x4 acc[4][4] = {};
  bf16x8 bc[2][4], bn[2][4];

  // ---- prologue: stage A(0); load B(0) to regs; stage A(1); vmcnt(10) ----
  stage_A(A, m0, 0,  As + 0 * ARSZ, w, tid);
  stage_A(A, m0, 32, As + 1 * ARSZ, w, tid);
#pragma unroll
  for (int kh = 0; kh < 2; ++kh)
#pragma unroll
    for (int f = 0; f < 4; ++f)
      bc[kh][f] = *(const bf16x8*)(bbase + (size_t)(f * 16) * DIM + kh * 32);
  stage_A(A, m0, 64, As + 2 * ARSZ, w, tid);
  stage_A(A, m0, 96, As + 3 * ARSZ, w, tid);
  asm volatile("s_waitcnt vmcnt(10)" ::: "memory");  // A(0) landed
  __builtin_amdgcn_s_barrier();

#pragma unroll 2
  for (int t = 0; t < NT; ++t) {
    const bf16* Abuf = As + (size_t)(t % 3) * (2 * ARSZ);

    // issue B(t+1) -> regs (8 x b128, L2-resident panel)
    if (t + 1 < NT) {
      const bf16* bsrc = bbase + (t + 1) * 64;
#pragma unroll
      for (int kh = 0; kh < 2; ++kh)
#pragma unroll
        for (int f = 0; f < 4; ++f)
          bn[kh][f] = *(const bf16x8*)(bsrc + (size_t)(f * 16) * DIM + kh * 32);
    }
    // issue A(t+2) -> LDS buf (t+2)%3 (2 x gload_lds)
    if (t + 2 < NT) {
      bf16* dst = As + (size_t)((t + 2) % 3) * (2 * ARSZ);
      stage_A(A, m0, (t + 2) * 64,      dst,        w, tid);
      stage_A(A, m0, (t + 2) * 64 + 32, dst + ARSZ, w, tid);
    }

    // compute tile t: per kh, read 4 A-frags from LDS, 16 MFMA with reg B
#pragma unroll
    for (int kh = 0; kh < 2; ++kh) {
      bf16x8 af[4];
#pragma unroll
      for (int f = 0; f < 4; ++f)
        af[f] = *(const bf16x8*)(Abuf + (size_t)kh * ARSZ +
                                 (size_t)(aoff + f * 16) * 32 + qc);
      __builtin_amdgcn_s_setprio(1);
#pragma unroll
      for (int mf = 0; mf < 4; ++mf)
#pragma unroll
        for (int nf = 0; nf < 4; ++nf)
          acc[mf][nf] = __builtin_amdgcn_mfma_f32_16x16x32_bf16(
              af[mf], bc[kh][nf], acc[mf][nf], 0, 0, 0);
      __builtin_amdgcn_s_setprio(0);
    }

    // counted drain: A(t+1) landed, newest 10 (B(t+1)x8 + A(t+2)x2) in flight
    if (t + 2 < NT)      asm volatile("s_waitcnt vmcnt(10)" ::: "memory");
    else if (t + 1 < NT) asm volatile("s_waitcnt vmcnt(8)" ::: "memory");
    __builtin_amdgcn_s_barrier();

#pragma unroll
    for (int kh = 0; kh < 2; ++kh)
#pragma unroll
      for (int f = 0; f < 4; ++f) bc[kh][f] = bn[kh][f];
  }

  // ---------------- epilogue: Q (RoPE*QSC) / K (RoPE) / V^T ----------------
  const int sel = n0 >> 11;  // bx 0-7: Q, 8-15: K, 16-23: V (block-uniform)
  if (sel == 2) {
#pragma unroll
    for (int mf = 0; mf < 4; ++mf)
#pragma unroll
      for (int nf = 0; nf < 4; ++nf) {
        int gr = m0 + wm * 64 + mf * 16 + quad * 4;
        int fc = (n0 + wn * 64 + nf * 16 + ln) & 2047;
        int bb = gr >> 11, s0 = gr & (SEQ - 1);
        int h = fc >> 7, d = fc & (HD - 1);
        bf16x4 pk;
#pragma unroll
        for (int r = 0; r < 4; ++r) pk[r] = (bf16)acc[mf][nf][r];
        *(bf16x4*)(VTo + ((size_t)((bb * NH + h) * HD + d)) * SEQ + s0) = pk;
      }
  } else {
    bf16* Dst = sel ? Kb : Qb;
    const float osc = sel ? 1.0f : QSC;
#pragma unroll
    for (int nf = 0; nf < 4; ++nf) {
      int gc = n0 + wn * 64 + nf * 16 + ln;
      int fc = gc & 2047, d = fc & (HD - 1);
      float freq = exp2f(-(float)(d >> 1) * FREQC);
      bool ev = !(d & 1);
#pragma unroll
      for (int mf = 0; mf < 4; ++mf) {
#pragma unroll
        for (int r = 0; r < 4; ++r) {
          int gr = m0 + wm * 64 + mf * 16 + quad * 4 + r;
          int s = gr & (SEQ - 1);
          float ang = (float)s * freq;
          float sn, cs;
          __sincosf(ang, &sn, &cs);
          float own = acc[mf][nf][r];
          float oth = __shfl_xor(own, 1);  // partner feature (d^1), lane ln^1
          float res = ev ? (own * cs - oth * sn) : (oth * sn + own * cs);
          Dst[(size_t)gr * DIM + fc] = (bf16)(res * osc);
        }
      }
    }
  }
}

// --------------------------------------------------------------------- GEMM
// C[M,N] = A * BT^T; MODE 2: C fp32 row-major (used for the Wo projection).
template <int MODE>
__global__ __launch_bounds__(256) void gemm_bt(const bf16* __restrict__ A,
                                               const bf16* __restrict__ BT,
                                               void* __restrict__ C) {
  __shared__ __attribute__((aligned(16))) bf16 As[128 * 64];
  __shared__ __attribute__((aligned(16))) bf16 Bs[128 * 64];
  const int tid = threadIdx.x;
  const int w = tid >> 6, lane = tid & 63;
  const int quad = lane >> 4, ln = lane & 15;
  const int m0 = blockIdx.y * 128, n0 = blockIdx.x * 128;
  const int wm = (w >> 1) * 64, wn = (w & 1) * 64;
  const int l7 = ln & 7;
  f32x4 acc[4][4] = {};

  for (int k0 = 0; k0 < DIM; k0 += 64) {
#pragma unroll
    for (int i = 0; i < 4; ++i) {
      const int c = i * 256 + tid;
      const int row = c >> 3, p = c & 7;
      LDS_ASYNC16(A  + (size_t)(m0 + row) * DIM + k0 + ((p ^ (row & 7)) * 8),
                  As + (size_t)(i * 256 + w * 64) * 8);
      LDS_ASYNC16(BT + (size_t)(n0 + row) * DIM + k0 + ((p ^ (row & 7)) * 8),
                  Bs + (size_t)(i * 256 + w * 64) * 8);
    }
    __syncthreads();
#pragma unroll
    for (int kh = 0; kh < 2; ++kh) {
      bf16x8 af[4], bfr[4];
#pragma unroll
      for (int t = 0; t < 4; ++t)
        af[t] = *(const bf16x8*)(As + (wm + t * 16 + ln) * 64 +
                                 (((kh * 4 + quad) ^ l7) * 8));
#pragma unroll
      for (int t = 0; t < 4; ++t)
        bfr[t] = *(const bf16x8*)(Bs + (wn + t * 16 + ln) * 64 +
                                  (((kh * 4 + quad) ^ l7) * 8));
#pragma unroll
      for (int mt = 0; mt < 4; ++mt)
#pragma unroll
        for (int nt = 0; nt < 4; ++nt)
          acc[mt][nt] = __builtin_amdgcn_mfma_f32_16x16x32_bf16(
              af[mt], bfr[nt], acc[mt][nt], 0, 0, 0);
    }
    __syncthreads();
  }

  if (MODE == 0) {
    bf16* Co = (bf16*)C;
#pragma unroll
    for (int mt = 0; mt < 4; ++mt)
#pragma unroll
      for (int nt = 0; nt < 4; ++nt) {
        int gr = m0 + wm + mt * 16 + quad * 4;
        int gc = n0 + wn + nt * 16 + ln;
#pragma unroll
        for (int r = 0; r < 4; ++r)
          Co[(size_t)(gr + r) * DIM + gc] = (bf16)acc[mt][nt][r];
      }
  } else {
    float* Co = (float*)C;
#pragma unroll
    for (int mt = 0; mt < 4; ++mt)
#pragma unroll
      for (int nt = 0; nt < 4; ++nt) {
        int gr = m0 + wm + mt * 16 + quad * 4;
        int gc = n0 + wn + nt * 16 + ln;
#pragma unroll
        for (int r = 0; r < 4; ++r)
          Co[(size_t)(gr + r) * DIM + gc] = acc[mt][nt][r];
      }
  }
}

// -------------------------- flash split-K chunk bookkeeping (chunk = 10 k-tiles)
// Per (b,h): t=0..4 direct (1 chunk); t=5..9: 2 chunks; t=10..14: 3; t=15: 4.
// 34 blocks/bh. Chunk 0 of a chunked tile writes unnormalized bf16 into O's
// final location; chunks >=1 go to Opart. All chunks write M/L.
__device__ __forceinline__ int ml_off(int t) {  // per-bh M/L slot base, stride 29
  return (t < 10) ? 2 * (t - 5) : (t < 15) ? 10 + 3 * (t - 10) : 25;
}
__device__ __forceinline__ int op_off(int t) {  // per-bh Opart slot base, stride 18
  return (t < 10) ? (t - 5) : (t < 15) ? 5 + 2 * (t - 10) : 15;
}

constexpr int PSTR = 72;
// 1-D grid, XCD-swizzled: lb = ((bh>>3)*34 + e)*8 + (bh&7), so lb%8 (the XCD
// on the 8-XCD round-robin) is constant per bh -> one bh's 1 MB of K/V stays
// in one XCD's L2 (4 bh x 1 MB per XCD) instead of being fetched by all 8.
__global__ __launch_bounds__(256) void flash_attn(
    const bf16* __restrict__ Q, const bf16* __restrict__ K,
    const bf16* __restrict__ VT, bf16* __restrict__ O,
    bf16* __restrict__ Opart, float* __restrict__ Mpart,
    float* __restrict__ Lpart) {
  __shared__ __attribute__((aligned(16))) bf16 Ks[64 * 128];
  __shared__ __attribute__((aligned(16))) bf16 VTs[128 * 64];
  __shared__ __attribute__((aligned(16))) bf16 Ps[4][32 * PSTR];
  const int tid = threadIdx.x;
  const int w = tid >> 6, lane = tid & 63, quad = lane >> 4, ln = lane & 15;
  const int lb = blockIdx.x;
  const int low3 = lb & 7, rest = lb >> 3;
  const int e = rest % 34;
  const int bh = (rest / 34) * 8 + low3;
  int t, c0, nc;
  if (e < 5)       { t = e;                  c0 = 0;               nc = 1; }
  else if (e < 15) { t = 5 + ((e - 5) >> 1); c0 = (e - 5) & 1;     nc = 2; }
  else if (e < 30) { int q = (e - 15) / 3;   t = 10 + q; c0 = (e - 15) - 3 * q; nc = 3; }
  else             { t = 15;                 c0 = e - 30;          nc = 4; }
  const int q0 = t * 128;
  const int ktN = 2 * (t + 1);
  const int kt0 = c0 * 10;
  const int kt1 = min(kt0 + 10, ktN);
  const bool chunked = (nc > 1);
  const int b = bh >> 4, h = bh & 15;

  bf16x8 qf[2][4];
#pragma unroll
  for (int mt = 0; mt < 2; ++mt)
#pragma unroll
    for (int kc = 0; kc < 4; ++kc)
      qf[mt][kc] = *(const bf16x8*)(Q + ((size_t)b * SEQ + q0 + w * 32 + mt * 16 + ln) * DIM +
                                    h * HD + kc * 32 + quad * 8);
  f32x4 o[2][8] = {};
  float mst[2][4], lst[2][4];
#pragma unroll
  for (int mt = 0; mt < 2; ++mt)
#pragma unroll
    for (int r = 0; r < 4; ++r) { mst[mt][r] = -1e30f; lst[mt][r] = 0.f; }

  for (int kt = kt0; kt < kt1; ++kt) {
    __syncthreads();
#pragma unroll
    for (int i = 0; i < 4; ++i) {
      const int c = i * 256 + tid;
      LDS_ASYNC16(K + ((size_t)b * SEQ + kt * 64 + (c >> 4)) * DIM + h * HD +
                      (((c & 15) ^ ((c >> 4) & 15)) * 8),
                  Ks + (size_t)(i * 256 + w * 64) * 8);
      LDS_ASYNC16(VT + ((size_t)((b * NH + h) * HD) + (c >> 3)) * SEQ + kt * 64 +
                      (((c & 7) ^ ((c >> 3) & 7)) * 8),
                  VTs + (size_t)(i * 256 + w * 64) * 8);
    }
    __syncthreads();

    // S = Q K^T (exp2 domain; scale pre-folded into Q)
    f32x4 s[2][4] = {};
#pragma unroll
    for (int nt = 0; nt < 4; ++nt) {
      bf16x8 kf[4];
#pragma unroll
      for (int kc = 0; kc < 4; ++kc)
        kf[kc] = *(const bf16x8*)(Ks + (nt * 16 + ln) * 128 +
                                  (((kc * 4 + quad) ^ ln) * 8));
#pragma unroll
      for (int kc = 0; kc < 4; ++kc)
#pragma unroll
        for (int mt = 0; mt < 2; ++mt)
          s[mt][nt] = __builtin_amdgcn_mfma_f32_16x16x32_bf16(
              qf[mt][kc], kf[kc], s[mt][nt], 0, 0, 0);
    }

    const bool diag = (kt * 64 + 63 > q0);
    if (diag) {
#pragma unroll
      for (int mt = 0; mt < 2; ++mt)
#pragma unroll
        for (int nt = 0; nt < 4; ++nt)
#pragma unroll
          for (int r = 0; r < 4; ++r) {
            int kg = kt * 64 + nt * 16 + ln;
            int qg = q0 + w * 32 + mt * 16 + quad * 4 + r;
            if (kg > qg) s[mt][nt][r] = -1e30f;
          }
    }

    // online softmax, exp2 domain; DPP 16-lane max (no LDS shuffles)
#pragma unroll
    for (int mt = 0; mt < 2; ++mt)
#pragma unroll
      for (int r = 0; r < 4; ++r) {
        float rm = fmaxf(fmaxf(s[mt][0][r], s[mt][1][r]),
                         fmaxf(s[mt][2][r], s[mt][3][r]));
        rm = rowmax16(rm);
        float mold = mst[mt][r];
        float mnew = fmaxf(mold, rm);
        float alpha = exp2f(mold - mnew);
        mst[mt][r] = mnew;
        float rs = 0.f;
#pragma unroll
        for (int nt = 0; nt < 4; ++nt) {
          float p = exp2f(s[mt][nt][r] - mnew);
          rs += p;
          Ps[w][(mt * 16 + quad * 4 + r) * PSTR + nt * 16 + ln] = (bf16)p;
        }
        lst[mt][r] = lst[mt][r] * alpha + rs;
#pragma unroll
        for (int nd = 0; nd < 8; ++nd) o[mt][nd][r] *= alpha;
      }
    __syncthreads();

    // O += P V
#pragma unroll
    for (int kc2 = 0; kc2 < 2; ++kc2) {
      bf16x8 pf[2];
#pragma unroll
      for (int mt = 0; mt < 2; ++mt)
        pf[mt] = *(const bf16x8*)(&Ps[w][(mt * 16 + ln) * PSTR + kc2 * 32 + quad * 8]);
#pragma unroll
      for (int nd = 0; nd < 8; ++nd) {
        bf16x8 vf = *(const bf16x8*)(VTs + (nd * 16 + ln) * 64 +
                                     (((kc2 * 4 + quad) ^ (ln & 7)) * 8));
#pragma unroll
        for (int mt = 0; mt < 2; ++mt)
          o[mt][nd] = __builtin_amdgcn_mfma_f32_16x16x32_bf16(
              pf[mt], vf, o[mt][nd], 0, 0, 0);
      }
    }
  }

  if (!chunked) {
#pragma unroll
    for (int mt = 0; mt < 2; ++mt)
#pragma unroll
      for (int r = 0; r < 4; ++r) {
        float inv = 1.f / rowsum16(lst[mt][r]);
        int qg = q0 + w * 32 + mt * 16 + quad * 4 + r;
#pragma unroll
        for (int nd = 0; nd < 8; ++nd)
          O[((size_t)b * SEQ + qg) * DIM + h * HD + nd * 16 + ln] =
              (bf16)(o[mt][nd][r] * inv);
      }
  } else {
    const int mls = bh * 29 + ml_off(t) + c0;
    bf16* Op = (c0 == 0) ? nullptr
                         : Opart + (size_t)(bh * 18 + op_off(t) + (c0 - 1)) * (128 * 128);
#pragma unroll
    for (int mt = 0; mt < 2; ++mt)
#pragma unroll
      for (int r = 0; r < 4; ++r) {
        float l = rowsum16(lst[mt][r]);
        int qr = w * 32 + mt * 16 + quad * 4 + r;
        if (ln == 0) {
          Mpart[mls * 128 + qr] = mst[mt][r];
          Lpart[mls * 128 + qr] = l;
        }
        if (c0 == 0) {
#pragma unroll
          for (int nd = 0; nd < 8; ++nd)
            O[((size_t)b * SEQ + q0 + qr) * DIM + h * HD + nd * 16 + ln] =
                (bf16)o[mt][nd][r];
        } else {
#pragma unroll
          for (int nd = 0; nd < 8; ++nd)
            Op[qr * 128 + nd * 16 + ln] = (bf16)o[mt][nd][r];
        }
      }
  }
}

// ----------------------------------------------------- merge split-K partials
// grid (32, 11): bh x (t-5). Chunk 0 lives unnormalized in O; chunks 1..nc-1
// in Opart. Combine with max-rebased weights, normalize, write O.
__global__ __launch_bounds__(256) void flash_merge(const bf16* __restrict__ Opart,
                                                   const float* __restrict__ Mpart,
                                                   const float* __restrict__ Lpart,
                                                   bf16* __restrict__ O) {
  const int bh = blockIdx.x;
  const int t = 5 + blockIdx.y;
  const int nc = (t < 10) ? 2 : (t < 15) ? 3 : 4;
  const int b = bh >> 4, h = bh & 15;
  const int row = threadIdx.x >> 1, half = threadIdx.x & 1;
  const int mlb = bh * 29 + ml_off(t);
  float m[4], l[4], wt[4];
  float M = -1e30f;
  for (int c = 0; c < nc; ++c) {
    m[c] = Mpart[(mlb + c) * 128 + row];
    l[c] = Lpart[(mlb + c) * 128 + row];
    M = fmaxf(M, m[c]);
  }
  float wsum = 0.f;
  for (int c = 0; c < nc; ++c) { wt[c] = exp2f(m[c] - M); wsum += wt[c] * l[c]; }
  const float inv = 1.f / wsum;
  bf16* dst = O + ((size_t)b * SEQ + t * 128 + row) * DIM + h * HD + half * 64;
  const bf16* pb = Opart + (size_t)(bh * 18 + op_off(t)) * (128 * 128) + row * 128 + half * 64;
#pragma unroll
  for (int j = 0; j < 8; ++j) {
    bf16x8 a0 = *(const bf16x8*)(dst + j * 8);
    float acc[8];
#pragma unroll
    for (int k = 0; k < 8; ++k) acc[k] = wt[0] * (float)a0[k];
    for (int c = 1; c < nc; ++c) {
      bf16x8 a = *(const bf16x8*)(pb + (size_t)(c - 1) * (128 * 128) + j * 8);
#pragma unroll
      for (int k = 0; k < 8; ++k) acc[k] += wt[c] * (float)a[k];
    }
    bf16x8 o8;
#pragma unroll
    for (int k = 0; k < 8; ++k) o8[k] = (bf16)(acc[k] * inv);
    *(bf16x8*)(dst + j * 8) = o8;
  }
}

// ------------------------------------------------------------------- launch
extern "C" void kernel_launch(void* const* d_in, const int* in_sizes, int n_in,
                              void* d_out, int out_size, void* d_ws, size_t ws_size,
                              hipStream_t stream) {
  (void)in_sizes; (void)n_in; (void)out_size; (void)ws_size;
  const float* x  = (const float*)d_in[0];
  const float* Wq = (const float*)d_in[1];
  const float* Wk = (const float*)d_in[2];
  const float* Wv = (const float*)d_in[3];
  const float* Wo = (const float*)d_in[4];

  char* ws = (char*)d_ws;
  const size_t MB = 1u << 20;
  const size_t WB = (size_t)DIM * DIM * 2;  // 8 MB
  bf16* WTqkv = (bf16*)(ws);                // 24 MB; dead after gemm_qkv
  bf16* WoT   = (bf16*)(ws + 3 * WB);       // 8 MB
  bf16* xb    = (bf16*)(ws + 32 * MB);      // 16 MB; Ab aliases after QKV
  bf16* Qb    = (bf16*)(ws + 48 * MB);
  bf16* Kb    = (bf16*)(ws + 64 * MB);
  bf16* VT    = (bf16*)(ws + 80 * MB);
  bf16* Ab    = xb;
  // split-K partials alias the (dead) WTqkv region:
  // Opart 18.9 MB (32 bh x 18 slots x 32 KB) + M/L ~0.5 MB each
  bf16*  Opart = (bf16*)(ws);
  float* Mpart = (float*)(ws + 19 * MB);
  float* Lpart = (float*)(ws + 19 * MB + 512 * 1024);

  int n4 = BATCH * SEQ * DIM / 4;
  cvt_f32_to_bf16<<<n4 / 256, 256, 0, stream>>>((const float4*)x, (bf16x4*)xb, n4);
  dim3 tb(32, 8), tg(DIM / 32, DIM / 32, 4);
  transpose_w4<<<tg, tb, 0, stream>>>(Wq, Wk, Wv, Wo, WTqkv, WoT);

  // 128x256 B-direct QKV: 768 blocks = exactly 3 rounds of 256 CUs
  gemm_qkv<<<768, 512, 0, stream>>>(xb, WTqkv, Qb, Kb, VT);

  // 1-D XCD-swizzled flash grid: 34 chunks x 32 bh
  flash_attn<<<34 * BATCH * NH, 256, 0, stream>>>(Qb, Kb, VT, Ab, Opart, Mpart, Lpart);
  dim3 mg(BATCH * NH, 11);
  flash_merge<<<mg, 256, 0, stream>>>(Opart, Mpart, Lpart, Ab);

  dim3 gg(DIM / 128, BATCH * SEQ / 128);
  gemm_bt<2><<<gg, 256, 0, stream>>>(Ab, WoT, d_out);
}

// Round 6
// 547.043 us; speedup vs baseline: 1.0008x; 1.0008x over previous
//
#include <hip/hip_runtime.h>
#include <hip/hip_bf16.h>
#include <math.h>

typedef __bf16 bf16;
typedef __attribute__((ext_vector_type(2))) __bf16 bf16x2;
typedef __attribute__((ext_vector_type(4))) __bf16 bf16x4;
typedef __attribute__((ext_vector_type(8))) __bf16 bf16x8;
typedef __attribute__((ext_vector_type(4))) float f32x4;

#define LDS_ASYNC16(gptr, lptr)                                                        \
  __builtin_amdgcn_global_load_lds(                                                    \
      (const __attribute__((address_space(1))) void*)(gptr),                           \
      (__attribute__((address_space(3))) void*)(lptr), 16, 0, 0)

constexpr int BATCH = 2, SEQ = 2048, DIM = 2048, NH = 16, HD = 128;
// 1/sqrt(128) * log2(e): folded into Q at projection; flash works in exp2 domain
constexpr float QSC = 0.12751744f;
constexpr float FREQC = 0.20762050593046f;  // log2(10000)/64

// ---- DPP 16-lane reductions (row_ror rotates within 16-lane rows on gfx9) ----
template <int CTRL>
__device__ __forceinline__ float dpp_mov_f(float x) {
  return __int_as_float(__builtin_amdgcn_update_dpp(
      __float_as_int(x), __float_as_int(x), CTRL, 0xf, 0xf, false));
}
__device__ __forceinline__ float rowmax16(float x) {
  x = fmaxf(x, dpp_mov_f<0x121>(x));  // ror:1
  x = fmaxf(x, dpp_mov_f<0x122>(x));  // ror:2
  x = fmaxf(x, dpp_mov_f<0x124>(x));  // ror:4
  x = fmaxf(x, dpp_mov_f<0x128>(x));  // ror:8
  return x;
}
__device__ __forceinline__ float rowsum16(float x) {
  x += dpp_mov_f<0x121>(x);
  x += dpp_mov_f<0x122>(x);
  x += dpp_mov_f<0x124>(x);
  x += dpp_mov_f<0x128>(x);
  return x;
}

// ---------------------------------------------------------------- fp32 -> bf16
__global__ void cvt_f32_to_bf16(const float4* __restrict__ in,
                                bf16x4* __restrict__ out, int n4) {
  int i = blockIdx.x * blockDim.x + threadIdx.x;
  if (i >= n4) return;
  float4 v = in[i];
  bf16x4 o;
  o[0] = (bf16)v.x; o[1] = (bf16)v.y; o[2] = (bf16)v.z; o[3] = (bf16)v.w;
  out[i] = o;
}

// ------------------------- all 4 weights: W (K,N) fp32 -> W^T (N,K) bf16, z=which
__global__ void transpose_w4(const float* __restrict__ W0, const float* __restrict__ W1,
                             const float* __restrict__ W2, const float* __restrict__ W3,
                             bf16* __restrict__ T0, bf16* __restrict__ T3) {
  __shared__ float tile[32][33];
  const int z = blockIdx.z;
  const float* W = (z == 0) ? W0 : (z == 1) ? W1 : (z == 2) ? W2 : W3;
  bf16* WT = (z == 3) ? T3 : (T0 + (size_t)z * DIM * DIM);
  int tx = threadIdx.x, ty = threadIdx.y;
  int bx = blockIdx.x * 32, by = blockIdx.y * 32;
#pragma unroll
  for (int j = 0; j < 32; j += 8)
    tile[ty + j][tx] = W[(size_t)(by + ty + j) * DIM + bx + tx];
  __syncthreads();
#pragma unroll
  for (int j = 0; j < 32; j += 8)
    WT[(size_t)(bx + ty + j) * DIM + by + tx] = (bf16)tile[tx][ty + j];
}

// ====== 128x256 fused QKV GEMM + RoPE, B-direct-from-global (R5 debugged) ======
// R5's concept (B in VGPRs, never LDS -> LDS traffic/tile 256KB->80KB) failed on
// two implementation bugs, both fixed here:
//  BUG1: A-read bank conflicts (6.3M = 4 cyc/read): dropped swizzle. FIX: R3's
//        proven chunk-XOR scheme (0 conflicts measured): stage source chunk
//        kc=(u&3)^((u>>3)&3); read phys chunk pc=(quad^((ln>>1)&3))*8.
//  BUG2: per-tile bc=bn register copy forced compiler drain of all 8 B-loads
//        each tile (copy consumes bn -> implicit vmcnt(2) at tile end). FIX:
//        unroll x2 with NAMED buffers bA/bB -> no copy; compiler emits a
//        counted vmcnt before B's first MFMA use (1 tile of latency cover).
// Geometry: BM=128,BN=256,BK=64; 512thr = 8 waves (2M x 4N), wave 64x64,
// acc 4x4. Grid 32x24 = 768 = exactly 3 rounds of 256 CUs.
// LDS: A only, 3 bufs x 2 kh x [128r][32k] (8 KB) = 48 KB. 3-buf rotation:
// stage A(t+2) targets buf read at t-1, done before the t-1 end barrier ->
// ONE barrier per tile.
// vmcnt ledger (issue order per tile: B(t+1)x8 regs, A(t+2)x2 gload_lds):
//   end of tile t: in-flight newest 10 = {B(t+1)x8, A(t+2)x2}; A(t+1)x2 are
//   older -> vmcnt(10) lands them. Tail: t=NT-2 -> vmcnt(8); t=NT-1 none.
//   Prologue: B(0)x8, A(0)x2, A(1)x2 -> vmcnt(2) lands B(0)+A(0).
__device__ __forceinline__ void stage_A(const bf16* __restrict__ src, int m0, int ks,
                                        bf16* lds, int w, int tid) {
  const int row = tid >> 2;                       // 128 rows, 4 x 16B chunks/row
  const int kc = (tid & 3) ^ ((tid >> 3) & 3);    // inverse swizzle on SOURCE
  LDS_ASYNC16(src + (size_t)(m0 + row) * DIM + ks + kc * 8,
              lds + (size_t)(w * 64) * 8);        // linear LDS dest (+lane*16B)
}

__global__ __launch_bounds__(512) void gemm_qkv(const bf16* __restrict__ A,
                                                const bf16* __restrict__ BT,
                                                bf16* __restrict__ Qb,
                                                bf16* __restrict__ Kb,
                                                bf16* __restrict__ VTo) {
  constexpr int ARSZ = 128 * 32;  // 4096 elems = 8 KB per (buf,kh) region
  constexpr int NT = DIM / 64;    // 32 K-tiles
  __shared__ __attribute__((aligned(16))) bf16 As[3 * 2 * ARSZ];  // 48 KB
  const int tid = threadIdx.x;
  const int w = tid >> 6, lane = tid & 63;
  const int quad = lane >> 4, ln = lane & 15;
  const int wm = w >> 2, wn = w & 3;  // 2M x 4N wave grid
  // XCD-bijective swizzle: each XCD owns 8 by x 12 bx
  const int lb = blockIdx.x;
  const int xcd = lb & 7, i = lb >> 3;        // i in 0..95
  const int by = (xcd >> 1) * 8 + (i & 7);    // 0..31
  const int bx = (xcd & 1) * 12 + (i >> 3);   // 0..23
  const int m0 = by * 128, n0 = bx * 256;
  const int aoff = wm * 64 + ln;                // A frag row within block tile
  const int pc = (quad ^ ((ln >> 1) & 3)) * 8;  // swizzled read chunk (lane-const)
  const bf16* bbase = BT + (size_t)(n0 + wn * 64 + ln) * DIM + quad * 8;

  f32x4 acc[4][4] = {};
  bf16x8 bA[2][4], bB[2][4];

  // ---- prologue: B(0)->bA; stage A(0)->buf0, A(1)->buf1; vmcnt(2) ----
#pragma unroll
  for (int kh = 0; kh < 2; ++kh)
#pragma unroll
    for (int f = 0; f < 4; ++f)
      bA[kh][f] = *(const bf16x8*)(bbase + (size_t)(f * 16) * DIM + kh * 32);
  stage_A(A, m0, 0,  As + 0 * (2 * ARSZ),        w, tid);
  stage_A(A, m0, 32, As + 0 * (2 * ARSZ) + ARSZ, w, tid);
  stage_A(A, m0, 64, As + 1 * (2 * ARSZ),        w, tid);
  stage_A(A, m0, 96, As + 1 * (2 * ARSZ) + ARSZ, w, tid);
  asm volatile("s_waitcnt vmcnt(2)" ::: "memory");  // B(0)+A(0) landed
  __builtin_amdgcn_s_barrier();

#define TILE_BODY(T, BCUR, BNXT)                                                \
  {                                                                             \
    const int t_ = (T);                                                         \
    if (t_ + 1 < NT) {                                                          \
      const bf16* bsrc = bbase + (t_ + 1) * 64;                                 \
      _Pragma("unroll") for (int kh = 0; kh < 2; ++kh)                          \
        _Pragma("unroll") for (int f = 0; f < 4; ++f)                           \
          BNXT[kh][f] = *(const bf16x8*)(bsrc + (size_t)(f * 16) * DIM + kh * 32); \
    }                                                                           \
    if (t_ + 2 < NT) {                                                          \
      bf16* dst = As + (size_t)((t_ + 2) % 3) * (2 * ARSZ);                     \
      stage_A(A, m0, (t_ + 2) * 64,      dst,        w, tid);                   \
      stage_A(A, m0, (t_ + 2) * 64 + 32, dst + ARSZ, w, tid);                   \
    }                                                                           \
    const bf16* Abuf = As + (size_t)(t_ % 3) * (2 * ARSZ);                      \
    bf16x8 af[2][4];                                                            \
    _Pragma("unroll") for (int kh = 0; kh < 2; ++kh)                            \
      _Pragma("unroll") for (int f = 0; f < 4; ++f)                             \
        af[kh][f] = *(const bf16x8*)(Abuf + (size_t)kh * ARSZ +                 \
                                     (size_t)(aoff + f * 16) * 32 + pc);        \
    __builtin_amdgcn_s_setprio(1);                                              \
    _Pragma("unroll") for (int kh = 0; kh < 2; ++kh)                            \
      _Pragma("unroll") for (int mf = 0; mf < 4; ++mf)                          \
        _Pragma("unroll") for (int nf = 0; nf < 4; ++nf)                        \
          acc[mf][nf] = __builtin_amdgcn_mfma_f32_16x16x32_bf16(                \
              af[kh][mf], BCUR[kh][nf], acc[mf][nf], 0, 0, 0);                  \
    __builtin_amdgcn_s_setprio(0);                                              \
    if (t_ + 2 < NT)      asm volatile("s_waitcnt vmcnt(10)" ::: "memory");     \
    else if (t_ + 1 < NT) asm volatile("s_waitcnt vmcnt(8)" ::: "memory");      \
    __builtin_amdgcn_s_barrier();                                               \
  }

  for (int t = 0; t < NT; t += 2) {
    TILE_BODY(t,     bA, bB);
    TILE_BODY(t + 1, bB, bA);
  }
#undef TILE_BODY

  // ---------------- epilogue: Q (RoPE*QSC) / K (RoPE) / V^T ----------------
  const int sel = n0 >> 11;  // bx 0-7: Q, 8-15: K, 16-23: V (block-uniform)
  if (sel == 2) {
#pragma unroll
    for (int mf = 0; mf < 4; ++mf)
#pragma unroll
      for (int nf = 0; nf < 4; ++nf) {
        int gr = m0 + wm * 64 + mf * 16 + quad * 4;
        int fc = (n0 + wn * 64 + nf * 16 + ln) & 2047;
        int bb = gr >> 11, s0 = gr & (SEQ - 1);
        int h = fc >> 7, d = fc & (HD - 1);
        bf16x4 pk;
#pragma unroll
        for (int r = 0; r < 4; ++r) pk[r] = (bf16)acc[mf][nf][r];
        *(bf16x4*)(VTo + ((size_t)((bb * NH + h) * HD + d)) * SEQ + s0) = pk;
      }
  } else {
    bf16* Dst = sel ? Kb : Qb;
    const float osc = sel ? 1.0f : QSC;
#pragma unroll
    for (int nf = 0; nf < 4; ++nf) {
      int gc = n0 + wn * 64 + nf * 16 + ln;
      int fc = gc & 2047, d = fc & (HD - 1);
      float freq = exp2f(-(float)(d >> 1) * FREQC);
      bool ev = !(d & 1);
#pragma unroll
      for (int mf = 0; mf < 4; ++mf) {
#pragma unroll
        for (int r = 0; r < 4; ++r) {
          int gr = m0 + wm * 64 + mf * 16 + quad * 4 + r;
          int s = gr & (SEQ - 1);
          float ang = (float)s * freq;
          float sn, cs;
          __sincosf(ang, &sn, &cs);
          float own = acc[mf][nf][r];
          float oth = __shfl_xor(own, 1);  // partner feature (d^1), lane ln^1
          float res = ev ? (own * cs - oth * sn) : (oth * sn + own * cs);
          Dst[(size_t)gr * DIM + fc] = (bf16)(res * osc);
        }
      }
    }
  }
}

// --------------------------------------------------------------------- GEMM
// C[M,N] = A * BT^T; MODE 2: C fp32 row-major (used for the Wo projection).
template <int MODE>
__global__ __launch_bounds__(256) void gemm_bt(const bf16* __restrict__ A,
                                               const bf16* __restrict__ BT,
                                               void* __restrict__ C) {
  __shared__ __attribute__((aligned(16))) bf16 As[128 * 64];
  __shared__ __attribute__((aligned(16))) bf16 Bs[128 * 64];
  const int tid = threadIdx.x;
  const int w = tid >> 6, lane = tid & 63;
  const int quad = lane >> 4, ln = lane & 15;
  const int m0 = blockIdx.y * 128, n0 = blockIdx.x * 128;
  const int wm = (w >> 1) * 64, wn = (w & 1) * 64;
  const int l7 = ln & 7;
  f32x4 acc[4][4] = {};

  for (int k0 = 0; k0 < DIM; k0 += 64) {
#pragma unroll
    for (int i = 0; i < 4; ++i) {
      const int c = i * 256 + tid;
      const int row = c >> 3, p = c & 7;
      LDS_ASYNC16(A  + (size_t)(m0 + row) * DIM + k0 + ((p ^ (row & 7)) * 8),
                  As + (size_t)(i * 256 + w * 64) * 8);
      LDS_ASYNC16(BT + (size_t)(n0 + row) * DIM + k0 + ((p ^ (row & 7)) * 8),
                  Bs + (size_t)(i * 256 + w * 64) * 8);
    }
    __syncthreads();
#pragma unroll
    for (int kh = 0; kh < 2; ++kh) {
      bf16x8 af[4], bfr[4];
#pragma unroll
      for (int t = 0; t < 4; ++t)
        af[t] = *(const bf16x8*)(As + (wm + t * 16 + ln) * 64 +
                                 (((kh * 4 + quad) ^ l7) * 8));
#pragma unroll
      for (int t = 0; t < 4; ++t)
        bfr[t] = *(const bf16x8*)(Bs + (wn + t * 16 + ln) * 64 +
                                  (((kh * 4 + quad) ^ l7) * 8));
#pragma unroll
      for (int mt = 0; mt < 4; ++mt)
#pragma unroll
        for (int nt = 0; nt < 4; ++nt)
          acc[mt][nt] = __builtin_amdgcn_mfma_f32_16x16x32_bf16(
              af[mt], bfr[nt], acc[mt][nt], 0, 0, 0);
    }
    __syncthreads();
  }

  if (MODE == 0) {
    bf16* Co = (bf16*)C;
#pragma unroll
    for (int mt = 0; mt < 4; ++mt)
#pragma unroll
      for (int nt = 0; nt < 4; ++nt) {
        int gr = m0 + wm + mt * 16 + quad * 4;
        int gc = n0 + wn + nt * 16 + ln;
#pragma unroll
        for (int r = 0; r < 4; ++r)
          Co[(size_t)(gr + r) * DIM + gc] = (bf16)acc[mt][nt][r];
      }
  } else {
    float* Co = (float*)C;
#pragma unroll
    for (int mt = 0; mt < 4; ++mt)
#pragma unroll
      for (int nt = 0; nt < 4; ++nt) {
        int gr = m0 + wm + mt * 16 + quad * 4;
        int gc = n0 + wn + nt * 16 + ln;
#pragma unroll
        for (int r = 0; r < 4; ++r)
          Co[(size_t)(gr + r) * DIM + gc] = acc[mt][nt][r];
      }
  }
}

// -------------------------- flash split-K chunk bookkeeping (chunk = 10 k-tiles)
// Per (b,h): t=0..4 direct (1 chunk); t=5..9: 2 chunks; t=10..14: 3; t=15: 4.
// 34 blocks/bh. Chunk 0 of a chunked tile writes unnormalized bf16 into O's
// final location; chunks >=1 go to Opart. All chunks write M/L.
__device__ __forceinline__ int ml_off(int t) {  // per-bh M/L slot base, stride 29
  return (t < 10) ? 2 * (t - 5) : (t < 15) ? 10 + 3 * (t - 10) : 25;
}
__device__ __forceinline__ int op_off(int t) {  // per-bh Opart slot base, stride 18
  return (t < 10) ? (t - 5) : (t < 15) ? 5 + 2 * (t - 10) : 15;
}

constexpr int PSTR = 72;
// 1-D grid, XCD-swizzled: lb = ((bh>>3)*34 + e)*8 + (bh&7), so lb%8 (the XCD
// on the 8-XCD round-robin) is constant per bh -> one bh's 1 MB of K/V stays
// in one XCD's L2 (4 bh x 1 MB per XCD) instead of being fetched by all 8.
__global__ __launch_bounds__(256) void flash_attn(
    const bf16* __restrict__ Q, const bf16* __restrict__ K,
    const bf16* __restrict__ VT, bf16* __restrict__ O,
    bf16* __restrict__ Opart, float* __restrict__ Mpart,
    float* __restrict__ Lpart) {
  __shared__ __attribute__((aligned(16))) bf16 Ks[64 * 128];
  __shared__ __attribute__((aligned(16))) bf16 VTs[128 * 64];
  __shared__ __attribute__((aligned(16))) bf16 Ps[4][32 * PSTR];
  const int tid = threadIdx.x;
  const int w = tid >> 6, lane = tid & 63, quad = lane >> 4, ln = lane & 15;
  const int lb = blockIdx.x;
  const int low3 = lb & 7, rest = lb >> 3;
  const int e = rest % 34;
  const int bh = (rest / 34) * 8 + low3;
  int t, c0, nc;
  if (e < 5)       { t = e;                  c0 = 0;               nc = 1; }
  else if (e < 15) { t = 5 + ((e - 5) >> 1); c0 = (e - 5) & 1;     nc = 2; }
  else if (e < 30) { int q = (e - 15) / 3;   t = 10 + q; c0 = (e - 15) - 3 * q; nc = 3; }
  else             { t = 15;                 c0 = e - 30;          nc = 4; }
  const int q0 = t * 128;
  const int ktN = 2 * (t + 1);
  const int kt0 = c0 * 10;
  const int kt1 = min(kt0 + 10, ktN);
  const bool chunked = (nc > 1);
  const int b = bh >> 4, h = bh & 15;

  bf16x8 qf[2][4];
#pragma unroll
  for (int mt = 0; mt < 2; ++mt)
#pragma unroll
    for (int kc = 0; kc < 4; ++kc)
      qf[mt][kc] = *(const bf16x8*)(Q + ((size_t)b * SEQ + q0 + w * 32 + mt * 16 + ln) * DIM +
                                    h * HD + kc * 32 + quad * 8);
  f32x4 o[2][8] = {};
  float mst[2][4], lst[2][4];
#pragma unroll
  for (int mt = 0; mt < 2; ++mt)
#pragma unroll
    for (int r = 0; r < 4; ++r) { mst[mt][r] = -1e30f; lst[mt][r] = 0.f; }

  for (int kt = kt0; kt < kt1; ++kt) {
    __syncthreads();
#pragma unroll
    for (int i = 0; i < 4; ++i) {
      const int c = i * 256 + tid;
      LDS_ASYNC16(K + ((size_t)b * SEQ + kt * 64 + (c >> 4)) * DIM + h * HD +
                      (((c & 15) ^ ((c >> 4) & 15)) * 8),
                  Ks + (size_t)(i * 256 + w * 64) * 8);
      LDS_ASYNC16(VT + ((size_t)((b * NH + h) * HD) + (c >> 3)) * SEQ + kt * 64 +
                      (((c & 7) ^ ((c >> 3) & 7)) * 8),
                  VTs + (size_t)(i * 256 + w * 64) * 8);
    }
    __syncthreads();

    // S = Q K^T (exp2 domain; scale pre-folded into Q)
    f32x4 s[2][4] = {};
#pragma unroll
    for (int nt = 0; nt < 4; ++nt) {
      bf16x8 kf[4];
#pragma unroll
      for (int kc = 0; kc < 4; ++kc)
        kf[kc] = *(const bf16x8*)(Ks + (nt * 16 + ln) * 128 +
                                  (((kc * 4 + quad) ^ ln) * 8));
#pragma unroll
      for (int kc = 0; kc < 4; ++kc)
#pragma unroll
        for (int mt = 0; mt < 2; ++mt)
          s[mt][nt] = __builtin_amdgcn_mfma_f32_16x16x32_bf16(
              qf[mt][kc], kf[kc], s[mt][nt], 0, 0, 0);
    }

    const bool diag = (kt * 64 + 63 > q0);
    if (diag) {
#pragma unroll
      for (int mt = 0; mt < 2; ++mt)
#pragma unroll
        for (int nt = 0; nt < 4; ++nt)
#pragma unroll
          for (int r = 0; r < 4; ++r) {
            int kg = kt * 64 + nt * 16 + ln;
            int qg = q0 + w * 32 + mt * 16 + quad * 4 + r;
            if (kg > qg) s[mt][nt][r] = -1e30f;
          }
    }

    // online softmax, exp2 domain; DPP 16-lane max (no LDS shuffles)
#pragma unroll
    for (int mt = 0; mt < 2; ++mt)
#pragma unroll
      for (int r = 0; r < 4; ++r) {
        float rm = fmaxf(fmaxf(s[mt][0][r], s[mt][1][r]),
                         fmaxf(s[mt][2][r], s[mt][3][r]));
        rm = rowmax16(rm);
        float mold = mst[mt][r];
        float mnew = fmaxf(mold, rm);
        float alpha = exp2f(mold - mnew);
        mst[mt][r] = mnew;
        float rs = 0.f;
#pragma unroll
        for (int nt = 0; nt < 4; ++nt) {
          float p = exp2f(s[mt][nt][r] - mnew);
          rs += p;
          Ps[w][(mt * 16 + quad * 4 + r) * PSTR + nt * 16 + ln] = (bf16)p;
        }
        lst[mt][r] = lst[mt][r] * alpha + rs;
#pragma unroll
        for (int nd = 0; nd < 8; ++nd) o[mt][nd][r] *= alpha;
      }
    __syncthreads();

    // O += P V
#pragma unroll
    for (int kc2 = 0; kc2 < 2; ++kc2) {
      bf16x8 pf[2];
#pragma unroll
      for (int mt = 0; mt < 2; ++mt)
        pf[mt] = *(const bf16x8*)(&Ps[w][(mt * 16 + ln) * PSTR + kc2 * 32 + quad * 8]);
#pragma unroll
      for (int nd = 0; nd < 8; ++nd) {
        bf16x8 vf = *(const bf16x8*)(VTs + (nd * 16 + ln) * 64 +
                                     (((kc2 * 4 + quad) ^ (ln & 7)) * 8));
#pragma unroll
        for (int mt = 0; mt < 2; ++mt)
          o[mt][nd] = __builtin_amdgcn_mfma_f32_16x16x32_bf16(
              pf[mt], vf, o[mt][nd], 0, 0, 0);
      }
    }
  }

  if (!chunked) {
#pragma unroll
    for (int mt = 0; mt < 2; ++mt)
#pragma unroll
      for (int r = 0; r < 4; ++r) {
        float inv = 1.f / rowsum16(lst[mt][r]);
        int qg = q0 + w * 32 + mt * 16 + quad * 4 + r;
#pragma unroll
        for (int nd = 0; nd < 8; ++nd)
          O[((size_t)b * SEQ + qg) * DIM + h * HD + nd * 16 + ln] =
              (bf16)(o[mt][nd][r] * inv);
      }
  } else {
    const int mls = bh * 29 + ml_off(t) + c0;
    bf16* Op = (c0 == 0) ? nullptr
                         : Opart + (size_t)(bh * 18 + op_off(t) + (c0 - 1)) * (128 * 128);
#pragma unroll
    for (int mt = 0; mt < 2; ++mt)
#pragma unroll
      for (int r = 0; r < 4; ++r) {
        float l = rowsum16(lst[mt][r]);
        int qr = w * 32 + mt * 16 + quad * 4 + r;
        if (ln == 0) {
          Mpart[mls * 128 + qr] = mst[mt][r];
          Lpart[mls * 128 + qr] = l;
        }
        if (c0 == 0) {
#pragma unroll
          for (int nd = 0; nd < 8; ++nd)
            O[((size_t)b * SEQ + q0 + qr) * DIM + h * HD + nd * 16 + ln] =
                (bf16)o[mt][nd][r];
        } else {
#pragma unroll
          for (int nd = 0; nd < 8; ++nd)
            Op[qr * 128 + nd * 16 + ln] = (bf16)o[mt][nd][r];
        }
      }
  }
}

// ----------------------------------------------------- merge split-K partials
// grid (32, 11): bh x (t-5). Chunk 0 lives unnormalized in O; chunks 1..nc-1
// in Opart. Combine with max-rebased weights, normalize, write O.
__global__ __launch_bounds__(256) void flash_merge(const bf16* __restrict__ Opart,
                                                   const float* __restrict__ Mpart,
                                                   const float* __restrict__ Lpart,
                                                   bf16* __restrict__ O) {
  const int bh = blockIdx.x;
  const int t = 5 + blockIdx.y;
  const int nc = (t < 10) ? 2 : (t < 15) ? 3 : 4;
  const int b = bh >> 4, h = bh & 15;
  const int row = threadIdx.x >> 1, half = threadIdx.x & 1;
  const int mlb = bh * 29 + ml_off(t);
  float m[4], l[4], wt[4];
  float M = -1e30f;
  for (int c = 0; c < nc; ++c) {
    m[c] = Mpart[(mlb + c) * 128 + row];
    l[c] = Lpart[(mlb + c) * 128 + row];
    M = fmaxf(M, m[c]);
  }
  float wsum = 0.f;
  for (int c = 0; c < nc; ++c) { wt[c] = exp2f(m[c] - M); wsum += wt[c] * l[c]; }
  const float inv = 1.f / wsum;
  bf16* dst = O + ((size_t)b * SEQ + t * 128 + row) * DIM + h * HD + half * 64;
  const bf16* pb = Opart + (size_t)(bh * 18 + op_off(t)) * (128 * 128) + row * 128 + half * 64;
#pragma unroll
  for (int j = 0; j < 8; ++j) {
    bf16x8 a0 = *(const bf16x8*)(dst + j * 8);
    float acc[8];
#pragma unroll
    for (int k = 0; k < 8; ++k) acc[k] = wt[0] * (float)a0[k];
    for (int c = 1; c < nc; ++c) {
      bf16x8 a = *(const bf16x8*)(pb + (size_t)(c - 1) * (128 * 128) + j * 8);
#pragma unroll
      for (int k = 0; k < 8; ++k) acc[k] += wt[c] * (float)a[k];
    }
    bf16x8 o8;
#pragma unroll
    for (int k = 0; k < 8; ++k) o8[k] = (bf16)(acc[k] * inv);
    *(bf16x8*)(dst + j * 8) = o8;
  }
}

// ------------------------------------------------------------------- launch
extern "C" void kernel_launch(void* const* d_in, const int* in_sizes, int n_in,
                              void* d_out, int out_size, void* d_ws, size_t ws_size,
                              hipStream_t stream) {
  (void)in_sizes; (void)n_in; (void)out_size; (void)ws_size;
  const float* x  = (const float*)d_in[0];
  const float* Wq = (const float*)d_in[1];
  const float* Wk = (const float*)d_in[2];
  const float* Wv = (const float*)d_in[3];
  const float* Wo = (const float*)d_in[4];

  char* ws = (char*)d_ws;
  const size_t MB = 1u << 20;
  const size_t WB = (size_t)DIM * DIM * 2;  // 8 MB
  bf16* WTqkv = (bf16*)(ws);                // 24 MB; dead after gemm_qkv
  bf16* WoT   = (bf16*)(ws + 3 * WB);       // 8 MB
  bf16* xb    = (bf16*)(ws + 32 * MB);      // 16 MB; Ab aliases after QKV
  bf16* Qb    = (bf16*)(ws + 48 * MB);
  bf16* Kb    = (bf16*)(ws + 64 * MB);
  bf16* VT    = (bf16*)(ws + 80 * MB);
  bf16* Ab    = xb;
  // split-K partials alias the (dead) WTqkv region:
  // Opart 18.9 MB (32 bh x 18 slots x 32 KB) + M/L ~0.5 MB each
  bf16*  Opart = (bf16*)(ws);
  float* Mpart = (float*)(ws + 19 * MB);
  float* Lpart = (float*)(ws + 19 * MB + 512 * 1024);

  int n4 = BATCH * SEQ * DIM / 4;
  cvt_f32_to_bf16<<<n4 / 256, 256, 0, stream>>>((const float4*)x, (bf16x4*)xb, n4);
  dim3 tb(32, 8), tg(DIM / 32, DIM / 32, 4);
  transpose_w4<<<tg, tb, 0, stream>>>(Wq, Wk, Wv, Wo, WTqkv, WoT);

  // 128x256 B-direct QKV (debugged): 768 blocks = exactly 3 rounds of 256 CUs
  gemm_qkv<<<768, 512, 0, stream>>>(xb, WTqkv, Qb, Kb, VT);

  // 1-D XCD-swizzled flash grid: 34 chunks x 32 bh
  flash_attn<<<34 * BATCH * NH, 256, 0, stream>>>(Qb, Kb, VT, Ab, Opart, Mpart, Lpart);
  dim3 mg(BATCH * NH, 11);
  flash_merge<<<mg, 256, 0, stream>>>(Opart, Mpart, Lpart, Ab);

  dim3 gg(DIM / 128, BATCH * SEQ / 128);
  gemm_bt<2><<<gg, 256, 0, stream>>>(Ab, WoT, d_out);
}

// Round 7
// 427.864 us; speedup vs baseline: 1.2795x; 1.2785x over previous
//
#include <hip/hip_runtime.h>
#include <hip/hip_bf16.h>
#include <math.h>

typedef __bf16 bf16;
typedef __attribute__((ext_vector_type(2))) __bf16 bf16x2;
typedef __attribute__((ext_vector_type(4))) __bf16 bf16x4;
typedef __attribute__((ext_vector_type(8))) __bf16 bf16x8;
typedef __attribute__((ext_vector_type(4))) float f32x4;

#define LDS_ASYNC16(gptr, lptr)                                                        \
  __builtin_amdgcn_global_load_lds(                                                    \
      (const __attribute__((address_space(1))) void*)(gptr),                           \
      (__attribute__((address_space(3))) void*)(lptr), 16, 0, 0)

constexpr int BATCH = 2, SEQ = 2048, DIM = 2048, NH = 16, HD = 128;
// 1/sqrt(128) * log2(e): folded into Q at projection; flash works in exp2 domain
constexpr float QSC = 0.12751744f;
constexpr float FREQC = 0.20762050593046f;  // log2(10000)/64

// ---- DPP 16-lane reductions (row_ror rotates within 16-lane rows on gfx9) ----
template <int CTRL>
__device__ __forceinline__ float dpp_mov_f(float x) {
  return __int_as_float(__builtin_amdgcn_update_dpp(
      __float_as_int(x), __float_as_int(x), CTRL, 0xf, 0xf, false));
}
__device__ __forceinline__ float rowmax16(float x) {
  x = fmaxf(x, dpp_mov_f<0x121>(x));  // ror:1
  x = fmaxf(x, dpp_mov_f<0x122>(x));  // ror:2
  x = fmaxf(x, dpp_mov_f<0x124>(x));  // ror:4
  x = fmaxf(x, dpp_mov_f<0x128>(x));  // ror:8
  return x;
}
__device__ __forceinline__ float rowsum16(float x) {
  x += dpp_mov_f<0x121>(x);
  x += dpp_mov_f<0x122>(x);
  x += dpp_mov_f<0x124>(x);
  x += dpp_mov_f<0x128>(x);
  return x;
}

// ---------------------------------------------------------------- fp32 -> bf16
__global__ void cvt_f32_to_bf16(const float4* __restrict__ in,
                                bf16x4* __restrict__ out, int n4) {
  int i = blockIdx.x * blockDim.x + threadIdx.x;
  if (i >= n4) return;
  float4 v = in[i];
  bf16x4 o;
  o[0] = (bf16)v.x; o[1] = (bf16)v.y; o[2] = (bf16)v.z; o[3] = (bf16)v.w;
  out[i] = o;
}

// ------------------------- all 4 weights: W (K,N) fp32 -> W^T (N,K) bf16, z=which
__global__ void transpose_w4(const float* __restrict__ W0, const float* __restrict__ W1,
                             const float* __restrict__ W2, const float* __restrict__ W3,
                             bf16* __restrict__ T0, bf16* __restrict__ T3) {
  __shared__ float tile[32][33];
  const int z = blockIdx.z;
  const float* W = (z == 0) ? W0 : (z == 1) ? W1 : (z == 2) ? W2 : W3;
  bf16* WT = (z == 3) ? T3 : (T0 + (size_t)z * DIM * DIM);
  int tx = threadIdx.x, ty = threadIdx.y;
  int bx = blockIdx.x * 32, by = blockIdx.y * 32;
#pragma unroll
  for (int j = 0; j < 32; j += 8)
    tile[ty + j][tx] = W[(size_t)(by + ty + j) * DIM + bx + tx];
  __syncthreads();
#pragma unroll
  for (int j = 0; j < 32; j += 8)
    WT[(size_t)(bx + ty + j) * DIM + by + tx] = (bf16)tile[tx][ty + j];
}

// ======== 128x384 fused QKV GEMM + RoPE: zero-tail grid, wide wave tile ========
// R6 post-mortem: B-direct falsified (239us); R3's engine is ~1000 TF per-ACTIVE-
// CU (31% wall MfmaUtil / 0.75 grid utilization = 41% active, at the structural
// per-phase ceiling). The recoverable loss is the 384-block/256-CU TAIL (25%),
// not scheduling. Fix tail WITHOUT R2's read-ratio regression:
//   tile 128x384 -> grid 32x16 = 512 blocks = EXACTLY 2 rounds of 256 CUs.
//   8 waves (2M x 4N), wave tile 64x96, acc 4x6: per phase 24 MFMA / 10 ds_read
//   (ratio 0.42 ~ R3's 0.375; R2's 64x64 was 0.5 -> that was its loss).
// LDS 128 KB: regions [buf(2)][kh(2)]: A 128x32 (8 KB), B 384x32 (24 KB).
// Swizzle: R3/R6-verified pair (0 conflicts): stage source chunk
//   kc=(u&3)^((u>>3)&3); read phys chunk pc=(quad^((ln>>1)&3))*8. Valid here
//   since all row offsets (wm*64, wn*96, f*16) are multiples of 16 -> row==ln
//   (mod 16) and (row>>1)&3 == (ln>>1)&3.
// Schedule per tile t (buf=t&1), 2 phases, ONE vmcnt(8)+barrier per phase:
//   P1: read (buf,kh0) A4+B6; stage (t+1,kh1) [A1+B3=4 ops]; 24 MFMA;
//       vmcnt(8) -> lands (t,kh1) [staged (t-1).P1]  (tail t=NT-1: vmcnt(0))
//   P2: read (buf,kh1); stage (t+2,kh0) [4 ops]; 24 MFMA;
//       vmcnt(8) -> lands (t+1,kh0) [staged (t-1).P2] (tails: vmcnt(4) / none)
//   WAR: stage targets a region whose reads finished >=1 barrier earlier.
//   Ledger stack-walked for steady state + prologue + both tail tiles.
// Q/K/V split (2048) is NOT aligned to BN=384 -> epilogue selects Q/K/V per
// 16-wide fragment (fragments 16-aligned -> sel is fragment-uniform).
__device__ __forceinline__ void stage_A(const bf16* __restrict__ src, int m0, int ks,
                                        bf16* lds, int w, int tid) {
  const int row = tid >> 2;                     // 128 rows, 4 x 16B chunks/row
  const int kc = (tid & 3) ^ ((tid >> 3) & 3);  // inverse swizzle on SOURCE
  LDS_ASYNC16(src + (size_t)(m0 + row) * DIM + ks + kc * 8,
              lds + (size_t)(w * 64) * 8);      // linear LDS dest (+lane*16B)
}
__device__ __forceinline__ void stage_B384(const bf16* __restrict__ src, int n0, int ks,
                                           bf16* lds, int w, int tid) {
#pragma unroll
  for (int j = 0; j < 3; ++j) {                 // 3 instrs: 24 KB
    const int u = j * 512 + tid;                // 16B-slot 0..1535
    const int row = u >> 2;                     // 0..383
    const int kc = (u & 3) ^ ((u >> 3) & 3);
    LDS_ASYNC16(src + (size_t)(n0 + row) * DIM + ks + kc * 8,
                lds + (size_t)((j * 8 + w) * 64) * 8);
  }
}

__global__ __launch_bounds__(512) void gemm_qkv(const bf16* __restrict__ A,
                                                const bf16* __restrict__ BT,
                                                bf16* __restrict__ Qb,
                                                bf16* __restrict__ Kb,
                                                bf16* __restrict__ VTo) {
  constexpr int ARSZ = 128 * 32;   // 8 KB region
  constexpr int BRSZ = 384 * 32;   // 24 KB region
  constexpr int NT = DIM / 64;     // 32 K-tiles
  __shared__ __attribute__((aligned(16))) bf16 As[4 * ARSZ];  // 32 KB [buf*2+kh]
  __shared__ __attribute__((aligned(16))) bf16 Bs[4 * BRSZ];  // 96 KB [buf*2+kh]
  const int tid = threadIdx.x;
  const int w = tid >> 6, lane = tid & 63;
  const int quad = lane >> 4, ln = lane & 15;
  const int wm = w >> 2, wn = w & 3;  // 2M x 4N wave grid
  // XCD-bijective swizzle: each XCD owns 4 by-panels (2 MB A, L2-resident,
  // reused by its 16 bx-blocks) x 16 bx.
  const int lb = blockIdx.x;
  const int xcd = lb & 7, i = lb >> 3;     // i in 0..63
  const int by = xcd * 4 + (i & 3);        // 0..31
  const int bx = i >> 2;                   // 0..15
  const int m0 = by * 128, n0 = bx * 384;
  const int aoff = wm * 64 + ln;                // A frag row base
  const int boff = wn * 96 + ln;                // B frag row base
  const int pc = (quad ^ ((ln >> 1) & 3)) * 8;  // swizzled read chunk (lane-const)

  f32x4 acc[4][6] = {};

  // ---- prologue: stage (0,kh0) (0,kh1) (1,kh0); vmcnt(8) lands (0,kh0) ----
  stage_A  (A,  m0, 0,  As + 0 * ARSZ, w, tid);
  stage_B384(BT, n0, 0,  Bs + 0 * BRSZ, w, tid);
  stage_A  (A,  m0, 32, As + 1 * ARSZ, w, tid);
  stage_B384(BT, n0, 32, Bs + 1 * BRSZ, w, tid);
  stage_A  (A,  m0, 64, As + 2 * ARSZ, w, tid);
  stage_B384(BT, n0, 64, Bs + 2 * BRSZ, w, tid);
  asm volatile("s_waitcnt vmcnt(8)" ::: "memory");
  __builtin_amdgcn_s_barrier();

#pragma unroll 2
  for (int t = 0; t < NT; ++t) {
    const int b2 = (t & 1) * 2;
    bf16x8 af[4], bfr[6];

    // ---------------- P1: kh0 ----------------
#pragma unroll
    for (int f = 0; f < 4; ++f)
      af[f] = *(const bf16x8*)(As + (size_t)(b2 + 0) * ARSZ +
                               (size_t)(aoff + f * 16) * 32 + pc);
#pragma unroll
    for (int f = 0; f < 6; ++f)
      bfr[f] = *(const bf16x8*)(Bs + (size_t)(b2 + 0) * BRSZ +
                                (size_t)(boff + f * 16) * 32 + pc);
    if (t + 1 < NT) {
      const int r1 = ((t + 1) & 1) * 2 + 1;
      stage_A  (A,  m0, (t + 1) * 64 + 32, As + (size_t)r1 * ARSZ, w, tid);
      stage_B384(BT, n0, (t + 1) * 64 + 32, Bs + (size_t)r1 * BRSZ, w, tid);
    }
    __builtin_amdgcn_s_setprio(1);
#pragma unroll
    for (int mf = 0; mf < 4; ++mf)
#pragma unroll
      for (int nf = 0; nf < 6; ++nf)
        acc[mf][nf] = __builtin_amdgcn_mfma_f32_16x16x32_bf16(
            af[mf], bfr[nf], acc[mf][nf], 0, 0, 0);
    __builtin_amdgcn_s_setprio(0);
    if (t + 1 < NT) asm volatile("s_waitcnt vmcnt(8)" ::: "memory");
    else            asm volatile("s_waitcnt vmcnt(0)" ::: "memory");
    __builtin_amdgcn_s_barrier();

    // ---------------- P2: kh1 ----------------
#pragma unroll
    for (int f = 0; f < 4; ++f)
      af[f] = *(const bf16x8*)(As + (size_t)(b2 + 1) * ARSZ +
                               (size_t)(aoff + f * 16) * 32 + pc);
#pragma unroll
    for (int f = 0; f < 6; ++f)
      bfr[f] = *(const bf16x8*)(Bs + (size_t)(b2 + 1) * BRSZ +
                                (size_t)(boff + f * 16) * 32 + pc);
    if (t + 2 < NT) {
      stage_A  (A,  m0, (t + 2) * 64, As + (size_t)b2 * ARSZ, w, tid);
      stage_B384(BT, n0, (t + 2) * 64, Bs + (size_t)b2 * BRSZ, w, tid);
    }
    __builtin_amdgcn_s_setprio(1);
#pragma unroll
    for (int mf = 0; mf < 4; ++mf)
#pragma unroll
      for (int nf = 0; nf < 6; ++nf)
        acc[mf][nf] = __builtin_amdgcn_mfma_f32_16x16x32_bf16(
            af[mf], bfr[nf], acc[mf][nf], 0, 0, 0);
    __builtin_amdgcn_s_setprio(0);
    if (t + 2 < NT)      asm volatile("s_waitcnt vmcnt(8)" ::: "memory");
    else if (t + 1 < NT) asm volatile("s_waitcnt vmcnt(4)" ::: "memory");
    __builtin_amdgcn_s_barrier();
  }

  // -------- epilogue: per-fragment Q (RoPE*QSC) / K (RoPE) / V^T select --------
#pragma unroll
  for (int nf = 0; nf < 6; ++nf) {
    const int gc = n0 + wn * 96 + nf * 16 + ln;
    const int sel = gc >> 11;       // fragment-uniform (16-aligned fragments)
    const int fc = gc & 2047;
    if (sel == 2) {
      // V: write V^T (B, NH, HD, SEQ)
#pragma unroll
      for (int mf = 0; mf < 4; ++mf) {
        int gr = m0 + wm * 64 + mf * 16 + quad * 4;
        int bb = gr >> 11, s0 = gr & (SEQ - 1);
        int h = fc >> 7, d = fc & (HD - 1);
        bf16x4 pk;
#pragma unroll
        for (int r = 0; r < 4; ++r) pk[r] = (bf16)acc[mf][nf][r];
        *(bf16x4*)(VTo + ((size_t)((bb * NH + h) * HD + d)) * SEQ + s0) = pk;
      }
    } else {
      bf16* Dst = sel ? Kb : Qb;
      const float osc = sel ? 1.0f : QSC;
      const int d = fc & (HD - 1);
      const float freq = exp2f(-(float)(d >> 1) * FREQC);
      const bool ev = !(d & 1);
#pragma unroll
      for (int mf = 0; mf < 4; ++mf) {
#pragma unroll
        for (int r = 0; r < 4; ++r) {
          int gr = m0 + wm * 64 + mf * 16 + quad * 4 + r;
          int s = gr & (SEQ - 1);
          float ang = (float)s * freq;
          float sn, cs;
          __sincosf(ang, &sn, &cs);
          float own = acc[mf][nf][r];
          float oth = __shfl_xor(own, 1);  // partner feature (d^1), lane ln^1
          float res = ev ? (own * cs - oth * sn) : (oth * sn + own * cs);
          Dst[(size_t)gr * DIM + fc] = (bf16)(res * osc);
        }
      }
    }
  }
}

// --------------------------------------------------------------------- GEMM
// C[M,N] = A * BT^T; MODE 2: C fp32 row-major (used for the Wo projection).
template <int MODE>
__global__ __launch_bounds__(256) void gemm_bt(const bf16* __restrict__ A,
                                               const bf16* __restrict__ BT,
                                               void* __restrict__ C) {
  __shared__ __attribute__((aligned(16))) bf16 As[128 * 64];
  __shared__ __attribute__((aligned(16))) bf16 Bs[128 * 64];
  const int tid = threadIdx.x;
  const int w = tid >> 6, lane = tid & 63;
  const int quad = lane >> 4, ln = lane & 15;
  const int m0 = blockIdx.y * 128, n0 = blockIdx.x * 128;
  const int wm = (w >> 1) * 64, wn = (w & 1) * 64;
  const int l7 = ln & 7;
  f32x4 acc[4][4] = {};

  for (int k0 = 0; k0 < DIM; k0 += 64) {
#pragma unroll
    for (int i = 0; i < 4; ++i) {
      const int c = i * 256 + tid;
      const int row = c >> 3, p = c & 7;
      LDS_ASYNC16(A  + (size_t)(m0 + row) * DIM + k0 + ((p ^ (row & 7)) * 8),
                  As + (size_t)(i * 256 + w * 64) * 8);
      LDS_ASYNC16(BT + (size_t)(n0 + row) * DIM + k0 + ((p ^ (row & 7)) * 8),
                  Bs + (size_t)(i * 256 + w * 64) * 8);
    }
    __syncthreads();
#pragma unroll
    for (int kh = 0; kh < 2; ++kh) {
      bf16x8 af[4], bfr[4];
#pragma unroll
      for (int t = 0; t < 4; ++t)
        af[t] = *(const bf16x8*)(As + (wm + t * 16 + ln) * 64 +
                                 (((kh * 4 + quad) ^ l7) * 8));
#pragma unroll
      for (int t = 0; t < 4; ++t)
        bfr[t] = *(const bf16x8*)(Bs + (wn + t * 16 + ln) * 64 +
                                  (((kh * 4 + quad) ^ l7) * 8));
#pragma unroll
      for (int mt = 0; mt < 4; ++mt)
#pragma unroll
        for (int nt = 0; nt < 4; ++nt)
          acc[mt][nt] = __builtin_amdgcn_mfma_f32_16x16x32_bf16(
              af[mt], bfr[nt], acc[mt][nt], 0, 0, 0);
    }
    __syncthreads();
  }

  if (MODE == 0) {
    bf16* Co = (bf16*)C;
#pragma unroll
    for (int mt = 0; mt < 4; ++mt)
#pragma unroll
      for (int nt = 0; nt < 4; ++nt) {
        int gr = m0 + wm + mt * 16 + quad * 4;
        int gc = n0 + wn + nt * 16 + ln;
#pragma unroll
        for (int r = 0; r < 4; ++r)
          Co[(size_t)(gr + r) * DIM + gc] = (bf16)acc[mt][nt][r];
      }
  } else {
    float* Co = (float*)C;
#pragma unroll
    for (int mt = 0; mt < 4; ++mt)
#pragma unroll
      for (int nt = 0; nt < 4; ++nt) {
        int gr = m0 + wm + mt * 16 + quad * 4;
        int gc = n0 + wn + nt * 16 + ln;
#pragma unroll
        for (int r = 0; r < 4; ++r)
          Co[(size_t)(gr + r) * DIM + gc] = acc[mt][nt][r];
      }
  }
}

// -------------------------- flash split-K chunk bookkeeping (chunk = 10 k-tiles)
// Per (b,h): t=0..4 direct (1 chunk); t=5..9: 2 chunks; t=10..14: 3; t=15: 4.
// 34 blocks/bh. Chunk 0 of a chunked tile writes unnormalized bf16 into O's
// final location; chunks >=1 go to Opart. All chunks write M/L.
__device__ __forceinline__ int ml_off(int t) {  // per-bh M/L slot base, stride 29
  return (t < 10) ? 2 * (t - 5) : (t < 15) ? 10 + 3 * (t - 10) : 25;
}
__device__ __forceinline__ int op_off(int t) {  // per-bh Opart slot base, stride 18
  return (t < 10) ? (t - 5) : (t < 15) ? 5 + 2 * (t - 10) : 15;
}

constexpr int PSTR = 72;
// 1-D grid, XCD-swizzled: lb = ((bh>>3)*34 + e)*8 + (bh&7), so lb%8 (the XCD
// on the 8-XCD round-robin) is constant per bh -> one bh's 1 MB of K/V stays
// in one XCD's L2 (4 bh x 1 MB per XCD) instead of being fetched by all 8.
__global__ __launch_bounds__(256) void flash_attn(
    const bf16* __restrict__ Q, const bf16* __restrict__ K,
    const bf16* __restrict__ VT, bf16* __restrict__ O,
    bf16* __restrict__ Opart, float* __restrict__ Mpart,
    float* __restrict__ Lpart) {
  __shared__ __attribute__((aligned(16))) bf16 Ks[64 * 128];
  __shared__ __attribute__((aligned(16))) bf16 VTs[128 * 64];
  __shared__ __attribute__((aligned(16))) bf16 Ps[4][32 * PSTR];
  const int tid = threadIdx.x;
  const int w = tid >> 6, lane = tid & 63, quad = lane >> 4, ln = lane & 15;
  const int lb = blockIdx.x;
  const int low3 = lb & 7, rest = lb >> 3;
  const int e = rest % 34;
  const int bh = (rest / 34) * 8 + low3;
  int t, c0, nc;
  if (e < 5)       { t = e;                  c0 = 0;               nc = 1; }
  else if (e < 15) { t = 5 + ((e - 5) >> 1); c0 = (e - 5) & 1;     nc = 2; }
  else if (e < 30) { int q = (e - 15) / 3;   t = 10 + q; c0 = (e - 15) - 3 * q; nc = 3; }
  else             { t = 15;                 c0 = e - 30;          nc = 4; }
  const int q0 = t * 128;
  const int ktN = 2 * (t + 1);
  const int kt0 = c0 * 10;
  const int kt1 = min(kt0 + 10, ktN);
  const bool chunked = (nc > 1);
  const int b = bh >> 4, h = bh & 15;

  bf16x8 qf[2][4];
#pragma unroll
  for (int mt = 0; mt < 2; ++mt)
#pragma unroll
    for (int kc = 0; kc < 4; ++kc)
      qf[mt][kc] = *(const bf16x8*)(Q + ((size_t)b * SEQ + q0 + w * 32 + mt * 16 + ln) * DIM +
                                    h * HD + kc * 32 + quad * 8);
  f32x4 o[2][8] = {};
  float mst[2][4], lst[2][4];
#pragma unroll
  for (int mt = 0; mt < 2; ++mt)
#pragma unroll
    for (int r = 0; r < 4; ++r) { mst[mt][r] = -1e30f; lst[mt][r] = 0.f; }

  for (int kt = kt0; kt < kt1; ++kt) {
    __syncthreads();
#pragma unroll
    for (int i = 0; i < 4; ++i) {
      const int c = i * 256 + tid;
      LDS_ASYNC16(K + ((size_t)b * SEQ + kt * 64 + (c >> 4)) * DIM + h * HD +
                      (((c & 15) ^ ((c >> 4) & 15)) * 8),
                  Ks + (size_t)(i * 256 + w * 64) * 8);
      LDS_ASYNC16(VT + ((size_t)((b * NH + h) * HD) + (c >> 3)) * SEQ + kt * 64 +
                      (((c & 7) ^ ((c >> 3) & 7)) * 8),
                  VTs + (size_t)(i * 256 + w * 64) * 8);
    }
    __syncthreads();

    // S = Q K^T (exp2 domain; scale pre-folded into Q)
    f32x4 s[2][4] = {};
#pragma unroll
    for (int nt = 0; nt < 4; ++nt) {
      bf16x8 kf[4];
#pragma unroll
      for (int kc = 0; kc < 4; ++kc)
        kf[kc] = *(const bf16x8*)(Ks + (nt * 16 + ln) * 128 +
                                  (((kc * 4 + quad) ^ ln) * 8));
#pragma unroll
      for (int kc = 0; kc < 4; ++kc)
#pragma unroll
        for (int mt = 0; mt < 2; ++mt)
          s[mt][nt] = __builtin_amdgcn_mfma_f32_16x16x32_bf16(
              qf[mt][kc], kf[kc], s[mt][nt], 0, 0, 0);
    }

    const bool diag = (kt * 64 + 63 > q0);
    if (diag) {
#pragma unroll
      for (int mt = 0; mt < 2; ++mt)
#pragma unroll
        for (int nt = 0; nt < 4; ++nt)
#pragma unroll
          for (int r = 0; r < 4; ++r) {
            int kg = kt * 64 + nt * 16 + ln;
            int qg = q0 + w * 32 + mt * 16 + quad * 4 + r;
            if (kg > qg) s[mt][nt][r] = -1e30f;
          }
    }

    // online softmax, exp2 domain; DPP 16-lane max (no LDS shuffles)
#pragma unroll
    for (int mt = 0; mt < 2; ++mt)
#pragma unroll
      for (int r = 0; r < 4; ++r) {
        float rm = fmaxf(fmaxf(s[mt][0][r], s[mt][1][r]),
                         fmaxf(s[mt][2][r], s[mt][3][r]));
        rm = rowmax16(rm);
        float mold = mst[mt][r];
        float mnew = fmaxf(mold, rm);
        float alpha = exp2f(mold - mnew);
        mst[mt][r] = mnew;
        float rs = 0.f;
#pragma unroll
        for (int nt = 0; nt < 4; ++nt) {
          float p = exp2f(s[mt][nt][r] - mnew);
          rs += p;
          Ps[w][(mt * 16 + quad * 4 + r) * PSTR + nt * 16 + ln] = (bf16)p;
        }
        lst[mt][r] = lst[mt][r] * alpha + rs;
#pragma unroll
        for (int nd = 0; nd < 8; ++nd) o[mt][nd][r] *= alpha;
      }
    __syncthreads();

    // O += P V
#pragma unroll
    for (int kc2 = 0; kc2 < 2; ++kc2) {
      bf16x8 pf[2];
#pragma unroll
      for (int mt = 0; mt < 2; ++mt)
        pf[mt] = *(const bf16x8*)(&Ps[w][(mt * 16 + ln) * PSTR + kc2 * 32 + quad * 8]);
#pragma unroll
      for (int nd = 0; nd < 8; ++nd) {
        bf16x8 vf = *(const bf16x8*)(VTs + (nd * 16 + ln) * 64 +
                                     (((kc2 * 4 + quad) ^ (ln & 7)) * 8));
#pragma unroll
        for (int mt = 0; mt < 2; ++mt)
          o[mt][nd] = __builtin_amdgcn_mfma_f32_16x16x32_bf16(
              pf[mt], vf, o[mt][nd], 0, 0, 0);
      }
    }
  }

  if (!chunked) {
#pragma unroll
    for (int mt = 0; mt < 2; ++mt)
#pragma unroll
      for (int r = 0; r < 4; ++r) {
        float inv = 1.f / rowsum16(lst[mt][r]);
        int qg = q0 + w * 32 + mt * 16 + quad * 4 + r;
#pragma unroll
        for (int nd = 0; nd < 8; ++nd)
          O[((size_t)b * SEQ + qg) * DIM + h * HD + nd * 16 + ln] =
              (bf16)(o[mt][nd][r] * inv);
      }
  } else {
    const int mls = bh * 29 + ml_off(t) + c0;
    bf16* Op = (c0 == 0) ? nullptr
                         : Opart + (size_t)(bh * 18 + op_off(t) + (c0 - 1)) * (128 * 128);
#pragma unroll
    for (int mt = 0; mt < 2; ++mt)
#pragma unroll
      for (int r = 0; r < 4; ++r) {
        float l = rowsum16(lst[mt][r]);
        int qr = w * 32 + mt * 16 + quad * 4 + r;
        if (ln == 0) {
          Mpart[mls * 128 + qr] = mst[mt][r];
          Lpart[mls * 128 + qr] = l;
        }
        if (c0 == 0) {
#pragma unroll
          for (int nd = 0; nd < 8; ++nd)
            O[((size_t)b * SEQ + q0 + qr) * DIM + h * HD + nd * 16 + ln] =
                (bf16)o[mt][nd][r];
        } else {
#pragma unroll
          for (int nd = 0; nd < 8; ++nd)
            Op[qr * 128 + nd * 16 + ln] = (bf16)o[mt][nd][r];
        }
      }
  }
}

// ----------------------------------------------------- merge split-K partials
// grid (32, 11): bh x (t-5). Chunk 0 lives unnormalized in O; chunks 1..nc-1
// in Opart. Combine with max-rebased weights, normalize, write O.
__global__ __launch_bounds__(256) void flash_merge(const bf16* __restrict__ Opart,
                                                   const float* __restrict__ Mpart,
                                                   const float* __restrict__ Lpart,
                                                   bf16* __restrict__ O) {
  const int bh = blockIdx.x;
  const int t = 5 + blockIdx.y;
  const int nc = (t < 10) ? 2 : (t < 15) ? 3 : 4;
  const int b = bh >> 4, h = bh & 15;
  const int row = threadIdx.x >> 1, half = threadIdx.x & 1;
  const int mlb = bh * 29 + ml_off(t);
  float m[4], l[4], wt[4];
  float M = -1e30f;
  for (int c = 0; c < nc; ++c) {
    m[c] = Mpart[(mlb + c) * 128 + row];
    l[c] = Lpart[(mlb + c) * 128 + row];
    M = fmaxf(M, m[c]);
  }
  float wsum = 0.f;
  for (int c = 0; c < nc; ++c) { wt[c] = exp2f(m[c] - M); wsum += wt[c] * l[c]; }
  const float inv = 1.f / wsum;
  bf16* dst = O + ((size_t)b * SEQ + t * 128 + row) * DIM + h * HD + half * 64;
  const bf16* pb = Opart + (size_t)(bh * 18 + op_off(t)) * (128 * 128) + row * 128 + half * 64;
#pragma unroll
  for (int j = 0; j < 8; ++j) {
    bf16x8 a0 = *(const bf16x8*)(dst + j * 8);
    float acc[8];
#pragma unroll
    for (int k = 0; k < 8; ++k) acc[k] = wt[0] * (float)a0[k];
    for (int c = 1; c < nc; ++c) {
      bf16x8 a = *(const bf16x8*)(pb + (size_t)(c - 1) * (128 * 128) + j * 8);
#pragma unroll
      for (int k = 0; k < 8; ++k) acc[k] += wt[c] * (float)a[k];
    }
    bf16x8 o8;
#pragma unroll
    for (int k = 0; k < 8; ++k) o8[k] = (bf16)(acc[k] * inv);
    *(bf16x8*)(dst + j * 8) = o8;
  }
}

// ------------------------------------------------------------------- launch
extern "C" void kernel_launch(void* const* d_in, const int* in_sizes, int n_in,
                              void* d_out, int out_size, void* d_ws, size_t ws_size,
                              hipStream_t stream) {
  (void)in_sizes; (void)n_in; (void)out_size; (void)ws_size;
  const float* x  = (const float*)d_in[0];
  const float* Wq = (const float*)d_in[1];
  const float* Wk = (const float*)d_in[2];
  const float* Wv = (const float*)d_in[3];
  const float* Wo = (const float*)d_in[4];

  char* ws = (char*)d_ws;
  const size_t MB = 1u << 20;
  const size_t WB = (size_t)DIM * DIM * 2;  // 8 MB
  bf16* WTqkv = (bf16*)(ws);                // 24 MB; dead after gemm_qkv
  bf16* WoT   = (bf16*)(ws + 3 * WB);       // 8 MB
  bf16* xb    = (bf16*)(ws + 32 * MB);      // 16 MB; Ab aliases after QKV
  bf16* Qb    = (bf16*)(ws + 48 * MB);
  bf16* Kb    = (bf16*)(ws + 64 * MB);
  bf16* VT    = (bf16*)(ws + 80 * MB);
  bf16* Ab    = xb;
  // split-K partials alias the (dead) WTqkv region:
  // Opart 18.9 MB (32 bh x 18 slots x 32 KB) + M/L ~0.5 MB each
  bf16*  Opart = (bf16*)(ws);
  float* Mpart = (float*)(ws + 19 * MB);
  float* Lpart = (float*)(ws + 19 * MB + 512 * 1024);

  int n4 = BATCH * SEQ * DIM / 4;
  cvt_f32_to_bf16<<<n4 / 256, 256, 0, stream>>>((const float4*)x, (bf16x4*)xb, n4);
  dim3 tb(32, 8), tg(DIM / 32, DIM / 32, 4);
  transpose_w4<<<tg, tb, 0, stream>>>(Wq, Wk, Wv, Wo, WTqkv, WoT);

  // 128x384 zero-tail QKV: 512 blocks = exactly 2 rounds of 256 CUs
  gemm_qkv<<<512, 512, 0, stream>>>(xb, WTqkv, Qb, Kb, VT);

  // 1-D XCD-swizzled flash grid: 34 chunks x 32 bh
  flash_attn<<<34 * BATCH * NH, 256, 0, stream>>>(Qb, Kb, VT, Ab, Opart, Mpart, Lpart);
  dim3 mg(BATCH * NH, 11);
  flash_merge<<<mg, 256, 0, stream>>>(Opart, Mpart, Lpart, Ab);

  dim3 gg(DIM / 128, BATCH * SEQ / 128);
  gemm_bt<2><<<gg, 256, 0, stream>>>(Ab, WoT, d_out);
}